// Round 1
// baseline (304.024 us; speedup 1.0000x reference)
//
#include <hip/hip_runtime.h>
#include <math.h>

namespace {

constexpr int Bn = 8, Cn = 256, CIN = 128, Wd = 128, Hd = 128, ATTn = 32, Nn = ATTn * ATTn;

// ---------------- Kernel 1: adaptive max+avg pool of input1 -> p1[b][c][n] ----------------
__global__ __launch_bounds__(256) void pool1_kernel(const float* __restrict__ in,
                                                    float* __restrict__ p1) {
    int idx = blockIdx.x * 256 + threadIdx.x;       // B*C*N = 2,097,152 threads
    int ox = idx & 31;
    int oy = (idx >> 5) & 31;
    int bc = idx >> 10;                              // b*C + c
    const float* base = in + ((size_t)bc * Wd + oy * 4) * Hd + ox * 4;
    float mx = -INFINITY, sm = 0.f;
#pragma unroll
    for (int dy = 0; dy < 4; ++dy) {
        float4 v = *reinterpret_cast<const float4*>(base + dy * Hd);
        mx = fmaxf(mx, fmaxf(fmaxf(v.x, v.y), fmaxf(v.z, v.w)));
        sm += (v.x + v.y) + (v.z + v.w);
    }
    p1[idx] = mx + sm * (1.f / 16.f);
}

// ---------------- Kernel 2: fused 1x1-conv + max+avg pool -> p2t[b][n][c] ----------------
// One block per pooled cell (b, oy, ox): 16 pixels, each a 128->256 matvec.
__global__ __launch_bounds__(256) void convpool_kernel(const float* __restrict__ in2,
                                                       const float* __restrict__ cw,
                                                       const float* __restrict__ cb,
                                                       float* __restrict__ p2t) {
    __shared__ float lds_in[CIN][16];     // 8 KB : input window, [k][pixel]
    __shared__ float lds_wt[32][257];     // 32.9 KB : weight chunk transposed [k][c], +1 pad
    int cell = blockIdx.x;                // b*1024 + oy*32 + ox
    int ox = cell & 31, oy = (cell >> 5) & 31, b = cell >> 10;
    int t = threadIdx.x;                  // t = output channel c

    // stage input window: 128 k x 4 rows of float4
#pragma unroll
    for (int i = 0; i < 2; ++i) {
        int flat = t + i * 256;           // 0..511
        int k = flat >> 2, y = flat & 3;
        float4 v = *reinterpret_cast<const float4*>(
            in2 + (((size_t)(b * CIN + k) * Wd + (oy * 4 + y)) * Hd + ox * 4));
        *reinterpret_cast<float4*>(&lds_in[k][y * 4]) = v;
    }

    float acc[16];
#pragma unroll
    for (int p = 0; p < 16; ++p) acc[p] = 0.f;

    for (int ch = 0; ch < 4; ++ch) {
        int k0 = ch * 32;
        __syncthreads();                  // input visible (it=0) / prev chunk reads done
        // stage weight chunk transposed: 256 o x 32 k
#pragma unroll
        for (int i = 0; i < 8; ++i) {
            int flat4 = t + i * 256;      // 0..2047
            int o = flat4 >> 3, j4 = flat4 & 7;
            float4 v = *reinterpret_cast<const float4*>(cw + (size_t)o * CIN + k0 + j4 * 4);
            lds_wt[j4 * 4 + 0][o] = v.x;
            lds_wt[j4 * 4 + 1][o] = v.y;
            lds_wt[j4 * 4 + 2][o] = v.z;
            lds_wt[j4 * 4 + 3][o] = v.w;
        }
        __syncthreads();
#pragma unroll
        for (int k = 0; k < 32; ++k) {
            float wv = lds_wt[k][t];
#pragma unroll
            for (int p = 0; p < 16; ++p)
                acc[p] = fmaf(lds_in[k0 + k][p], wv, acc[p]);
        }
    }

    float bias = cb[t];
    float mx = -INFINITY, sm = 0.f;
#pragma unroll
    for (int p = 0; p < 16; ++p) {
        float v = acc[p] + bias;
        mx = fmaxf(mx, v);
        sm += v;
    }
    p2t[((size_t)b * Nn + (oy * 32 + ox)) * Cn + t] = mx + sm * (1.f / 16.f);
}

// ---------------- Kernel 3: per-cell cross-batch attention -> att[b][c][n] ----------------
__global__ __launch_bounds__(256) void attn_kernel(const float* __restrict__ p1,
                                                   const float* __restrict__ p2t,
                                                   float* __restrict__ att) {
    __shared__ float q[Bn][Cn + 1];
    __shared__ float kk[Bn][Cn + 1];
    __shared__ float wsm[Bn][8];
    int n = blockIdx.x, t = threadIdx.x;

#pragma unroll
    for (int i = 0; i < 8; ++i) {
        int flat = t + i * 256;           // 0..2047
        int bb = flat >> 8, c = flat & 255;
        q[bb][c]  = p1[((size_t)bb * Cn + c) * Nn + n];
        kk[bb][c] = p2t[((size_t)bb * Nn + n) * Cn + c];
    }
    __syncthreads();

    if (t < 64) {
        int bb = t >> 3, e = t & 7;
        float s = 0.f;
        for (int c = 0; c < Cn; ++c) s = fmaf(q[bb][c], kk[e][c], s);
        wsm[bb][e] = s * 0.17677669529663687f;   // 1/sqrt(32)
    }
    __syncthreads();

    if (t < 8) {
        float mx = -INFINITY;
#pragma unroll
        for (int e = 0; e < 8; ++e) mx = fmaxf(mx, wsm[t][e]);
        float sum = 0.f;
#pragma unroll
        for (int e = 0; e < 8; ++e) {
            float v = __expf(wsm[t][e] - mx);
            wsm[t][e] = v;
            sum += v;
        }
        float inv = 1.f / sum;
#pragma unroll
        for (int e = 0; e < 8; ++e) wsm[t][e] *= inv;
    }
    __syncthreads();

    float kv[8];
#pragma unroll
    for (int e = 0; e < 8; ++e) kv[e] = kk[e][t];
#pragma unroll
    for (int bb = 0; bb < 8; ++bb) {
        float s = 0.f;
#pragma unroll
        for (int e = 0; e < 8; ++e) s = fmaf(wsm[bb][e], kv[e], s);
        att[((size_t)bb * Cn + t) * Nn + n] = s;
    }
}

// ---------------- Kernel 4: bilinear upsample (align_corners) + sigmoid ----------------
__global__ __launch_bounds__(256) void upsample_kernel(const float* __restrict__ att,
                                                       float* __restrict__ out) {
    __shared__ float tile[ATTn * ATTn];   // 4 KB
    int bc = blockIdx.x, t = threadIdx.x;
    reinterpret_cast<float4*>(tile)[t] =
        reinterpret_cast<const float4*>(att + (size_t)bc * Nn)[t];
    __syncthreads();

    int tx = t & 31, ty = t >> 5;
    int xi0[4], xi1[4];
    float xt[4];
#pragma unroll
    for (int j = 0; j < 4; ++j) {
        int x = tx * 4 + j;
        float pos = (float)x * (31.f / 127.f);
        int i0 = (int)pos;
        xi0[j] = i0;
        xi1[j] = min(i0 + 1, 31);
        xt[j] = pos - (float)i0;
    }

    for (int r = 0; r < 16; ++r) {
        int y = ty + r * 8;
        float posy = (float)y * (31.f / 127.f);
        int y0 = (int)posy;
        int y1 = min(y0 + 1, 31);
        float ft = posy - (float)y0;
        float o_[4];
#pragma unroll
        for (int j = 0; j < 4; ++j) {
            float v00 = tile[y0 * 32 + xi0[j]];
            float v01 = tile[y0 * 32 + xi1[j]];
            float v10 = tile[y1 * 32 + xi0[j]];
            float v11 = tile[y1 * 32 + xi1[j]];
            float top = v00 * (1.f - ft) + v10 * ft;   // lerp along W (axis 2) first
            float bot = v01 * (1.f - ft) + v11 * ft;
            float val = top * (1.f - xt[j]) + bot * xt[j];
            o_[j] = 1.f / (1.f + __expf(-val));
        }
        *reinterpret_cast<float4*>(out + ((size_t)bc * Wd + y) * Hd + tx * 4) =
            make_float4(o_[0], o_[1], o_[2], o_[3]);
    }
}

}  // namespace

extern "C" void kernel_launch(void* const* d_in, const int* in_sizes, int n_in,
                              void* d_out, int out_size, void* d_ws, size_t ws_size,
                              hipStream_t stream) {
    const float* input1 = (const float*)d_in[0];
    const float* input2 = (const float*)d_in[1];
    const float* conv_w = (const float*)d_in[2];
    const float* conv_b = (const float*)d_in[3];
    float* out = (float*)d_out;

    float* p1  = (float*)d_ws;                        // 2M floats (8 MB)
    float* p2t = p1 + (size_t)Bn * Cn * Nn;           // 2M floats (8 MB)
    float* att = p2t + (size_t)Bn * Cn * Nn;          // 2M floats (8 MB)

    pool1_kernel<<<dim3(Bn * Cn * Nn / 256), dim3(256), 0, stream>>>(input1, p1);
    convpool_kernel<<<dim3(Bn * Nn), dim3(256), 0, stream>>>(input2, conv_w, conv_b, p2t);
    attn_kernel<<<dim3(Nn), dim3(256), 0, stream>>>(p1, p2t, att);
    upsample_kernel<<<dim3(Bn * Cn), dim3(256), 0, stream>>>(att, out);
}

// Round 2
// 124.344 us; speedup vs baseline: 2.4450x; 2.4450x over previous
//
#include <hip/hip_runtime.h>
#include <math.h>

namespace {

constexpr int Bn = 8, Cn = 256, CIN = 128, Wd = 128, Hd = 128, ATTn = 32, Nn = ATTn * ATTn;

typedef __attribute__((ext_vector_type(8))) short short8;
typedef __attribute__((ext_vector_type(4))) float f32x4;

__device__ inline unsigned short bf16_rne(float f) {
    unsigned int u = __float_as_uint(f);
    unsigned int r = (u + 0x7FFFu + ((u >> 16) & 1u)) >> 16;
    return (unsigned short)r;
}

// ---------------- Kernel 1: adaptive max+avg pool of input1 -> p1[b][c][n] ----------------
__global__ __launch_bounds__(256) void pool1_kernel(const float* __restrict__ in,
                                                    float* __restrict__ p1) {
    int idx = blockIdx.x * 256 + threadIdx.x;       // B*C*N threads
    int ox = idx & 31;
    int oy = (idx >> 5) & 31;
    int bc = idx >> 10;
    const float* base = in + ((size_t)bc * Wd + oy * 4) * Hd + ox * 4;
    float mx = -INFINITY, sm = 0.f;
#pragma unroll
    for (int dy = 0; dy < 4; ++dy) {
        float4 v = *reinterpret_cast<const float4*>(base + dy * Hd);
        mx = fmaxf(mx, fmaxf(fmaxf(v.x, v.y), fmaxf(v.z, v.w)));
        sm += (v.x + v.y) + (v.z + v.w);
    }
    p1[idx] = mx + sm * (1.f / 16.f);
}

// ---------------- Kernel 2: fused 1x1-conv (bf16 MFMA) + max+avg pool -> p2t[b][n][c] -------
// Block = half a pooled row: (b, oy, half) -> 16 cells. 8 waves, wave w owns out chans w*32..+31.
// Weights in registers (B-frags). Input staged 4 cells at a time, double-buffered, XOR-swizzled.
__global__ __launch_bounds__(512) void convpool_kernel(const float* __restrict__ in2,
                                                       const float* __restrict__ cw,
                                                       const float* __restrict__ cb,
                                                       float* __restrict__ p2t) {
    __shared__ __align__(16) unsigned char sIn[2][16384];   // [buf][4 cells][16 px][128 k] bf16

    const int t = threadIdx.x;            // 0..511
    const int w = t >> 6;                 // wave 0..7
    const int l = t & 63;                 // lane
    const int bid = blockIdx.x;
    const int b = bid >> 6;
    const int oy = (bid >> 1) & 31;
    const int half = bid & 1;

    const int n_lo = l & 15;
    const int khi = l >> 4;               // 0..3

    // ---- B fragments (weights) in registers: n = w*32 + f*16 + n_lo, k = kk*32 + khi*8 + j
    short8 bfrag[2][4];
#pragma unroll
    for (int f = 0; f < 2; ++f) {
        const int n = w * 32 + f * 16 + n_lo;
#pragma unroll
        for (int kk = 0; kk < 4; ++kk) {
            const float* wp = cw + n * CIN + kk * 32 + khi * 8;
            float4 va = *reinterpret_cast<const float4*>(wp);
            float4 vb = *reinterpret_cast<const float4*>(wp + 4);
            short8 s;
            s[0] = (short)bf16_rne(va.x); s[1] = (short)bf16_rne(va.y);
            s[2] = (short)bf16_rne(va.z); s[3] = (short)bf16_rne(va.w);
            s[4] = (short)bf16_rne(vb.x); s[5] = (short)bf16_rne(vb.y);
            s[6] = (short)bf16_rne(vb.z); s[7] = (short)bf16_rne(vb.w);
            bfrag[f][kk] = s;
        }
    }
    const float bias2_0 = 2.f * cb[w * 32 + n_lo];
    const float bias2_1 = 2.f * cb[w * 32 + 16 + n_lo];

    // ---- staging geometry: thread = (k4, dy, xq); loads 4 float4 (k = k4*4+i), 4x4 transpose
    const int xq = t & 3, dy = (t >> 2) & 3, k4 = t >> 4;   // k4 0..31
    const int row = oy * 4 + dy;
    const float* src = in2 + (((size_t)(b * CIN + k4 * 4)) * Wd + row) * Hd + half * 64 + xq * 4;

    float4 r0, r1, r2, r3;
#define STAGE_LOAD(g)                                                   \
    {   const float* p_ = src + (g) * 16;                               \
        r0 = *reinterpret_cast<const float4*>(p_);                      \
        r1 = *reinterpret_cast<const float4*>(p_ + Wd * Hd);            \
        r2 = *reinterpret_cast<const float4*>(p_ + 2 * Wd * Hd);        \
        r3 = *reinterpret_cast<const float4*>(p_ + 3 * Wd * Hd); }

#define WRQ(buf, dx, c0, c1, c2, c3)                                    \
    {   const int px_ = dy * 4 + (dx);                                  \
        uint2 u_;                                                       \
        u_.x = (unsigned int)bf16_rne(c0) | ((unsigned int)bf16_rne(c1) << 16); \
        u_.y = (unsigned int)bf16_rne(c2) | ((unsigned int)bf16_rne(c3) << 16); \
        const int off_ = (xq * 4096 + px_ * 256 + k4 * 8) ^ (((px_ & 7) << 4) ^ ((xq & 3) << 5)); \
        *reinterpret_cast<uint2*>(&sIn[buf][off_]) = u_; }

#define STAGE_WRITE(buf)                                                \
    {   WRQ(buf, 0, r0.x, r1.x, r2.x, r3.x)                             \
        WRQ(buf, 1, r0.y, r1.y, r2.y, r3.y)                             \
        WRQ(buf, 2, r0.z, r1.z, r2.z, r3.z)                             \
        WRQ(buf, 3, r0.w, r1.w, r2.w, r3.w) }

    STAGE_LOAD(0)
    STAGE_WRITE(0)
    __syncthreads();

    const int px = n_lo;                  // A-frag pixel row for this lane
    for (int g = 0; g < 4; ++g) {
        const int buf = g & 1;
        if (g < 3) STAGE_LOAD(g + 1)

        const unsigned char* base = sIn[buf];
#pragma unroll
        for (int c = 0; c < 4; ++c) {
            const int swz = ((px & 7) << 4) ^ ((c & 3) << 5);
            f32x4 acc0 = {0.f, 0.f, 0.f, 0.f};
            f32x4 acc1 = {0.f, 0.f, 0.f, 0.f};
#pragma unroll
            for (int kk = 0; kk < 4; ++kk) {
                short8 a = *reinterpret_cast<const short8*>(
                    base + ((c * 4096 + px * 256 + kk * 64 + khi * 16) ^ swz));
                acc0 = __builtin_amdgcn_mfma_f32_16x16x32_bf16(a, bfrag[0][kk], acc0, 0, 0, 0);
                acc1 = __builtin_amdgcn_mfma_f32_16x16x32_bf16(a, bfrag[1][kk], acc1, 0, 0, 0);
            }
            // pool over 16 pixels: rows p = khi*4 + r in-lane, then xor-reduce over khi
            float mx0 = fmaxf(fmaxf(acc0[0], acc0[1]), fmaxf(acc0[2], acc0[3]));
            float sm0 = (acc0[0] + acc0[1]) + (acc0[2] + acc0[3]);
            float mx1 = fmaxf(fmaxf(acc1[0], acc1[1]), fmaxf(acc1[2], acc1[3]));
            float sm1 = (acc1[0] + acc1[1]) + (acc1[2] + acc1[3]);
            mx0 = fmaxf(mx0, __shfl_xor(mx0, 16)); sm0 += __shfl_xor(sm0, 16);
            mx0 = fmaxf(mx0, __shfl_xor(mx0, 32)); sm0 += __shfl_xor(sm0, 32);
            mx1 = fmaxf(mx1, __shfl_xor(mx1, 16)); sm1 += __shfl_xor(sm1, 16);
            mx1 = fmaxf(mx1, __shfl_xor(mx1, 32)); sm1 += __shfl_xor(sm1, 32);
            if (l < 16) {
                const int cell = oy * 32 + half * 16 + g * 4 + c;
                float* dst = p2t + ((size_t)b * Nn + cell) * Cn + w * 32 + n_lo;
                dst[0]  = mx0 + sm0 * (1.f / 16.f) + bias2_0;
                dst[16] = mx1 + sm1 * (1.f / 16.f) + bias2_1;
            }
        }

        if (g < 3) STAGE_WRITE((g + 1) & 1)
        __syncthreads();
    }
#undef STAGE_LOAD
#undef STAGE_WRITE
#undef WRQ
}

// ---------------- Kernel 3: per-cell cross-batch attention -> att[b][c][n] ----------------
__global__ __launch_bounds__(256) void attn_kernel(const float* __restrict__ p1,
                                                   const float* __restrict__ p2t,
                                                   float* __restrict__ att) {
    __shared__ float q[Bn][Cn + 1];
    __shared__ float kk[Bn][Cn + 1];
    __shared__ float wsm[Bn][8];
    int n = blockIdx.x, t = threadIdx.x;

#pragma unroll
    for (int i = 0; i < 8; ++i) {
        int flat = t + i * 256;
        int bb = flat >> 8, c = flat & 255;
        q[bb][c]  = p1[((size_t)bb * Cn + c) * Nn + n];
        kk[bb][c] = p2t[((size_t)bb * Nn + n) * Cn + c];
    }
    __syncthreads();

    if (t < 64) {
        int bb = t >> 3, e = t & 7;
        float s = 0.f;
        for (int c = 0; c < Cn; ++c) s = fmaf(q[bb][c], kk[e][c], s);
        wsm[bb][e] = s * 0.17677669529663687f;   // 1/sqrt(32)
    }
    __syncthreads();

    if (t < 8) {
        float mx = -INFINITY;
#pragma unroll
        for (int e = 0; e < 8; ++e) mx = fmaxf(mx, wsm[t][e]);
        float sum = 0.f;
#pragma unroll
        for (int e = 0; e < 8; ++e) {
            float v = __expf(wsm[t][e] - mx);
            wsm[t][e] = v;
            sum += v;
        }
        float inv = 1.f / sum;
#pragma unroll
        for (int e = 0; e < 8; ++e) wsm[t][e] *= inv;
    }
    __syncthreads();

    float kv[8];
#pragma unroll
    for (int e = 0; e < 8; ++e) kv[e] = kk[e][t];
#pragma unroll
    for (int bb = 0; bb < 8; ++bb) {
        float s = 0.f;
#pragma unroll
        for (int e = 0; e < 8; ++e) s = fmaf(wsm[bb][e], kv[e], s);
        att[((size_t)bb * Cn + t) * Nn + n] = s;
    }
}

// ---------------- Kernel 4: bilinear upsample (align_corners) + sigmoid ----------------
__global__ __launch_bounds__(256) void upsample_kernel(const float* __restrict__ att,
                                                       float* __restrict__ out) {
    __shared__ float tile[ATTn * ATTn];
    int bc = blockIdx.x, t = threadIdx.x;
    reinterpret_cast<float4*>(tile)[t] =
        reinterpret_cast<const float4*>(att + (size_t)bc * Nn)[t];
    __syncthreads();

    int tx = t & 31, ty = t >> 5;
    int xi0[4], xi1[4];
    float xt[4];
#pragma unroll
    for (int j = 0; j < 4; ++j) {
        int x = tx * 4 + j;
        float pos = (float)x * (31.f / 127.f);
        int i0 = (int)pos;
        xi0[j] = i0;
        xi1[j] = min(i0 + 1, 31);
        xt[j] = pos - (float)i0;
    }

    for (int r = 0; r < 16; ++r) {
        int y = ty + r * 8;
        float posy = (float)y * (31.f / 127.f);
        int y0 = (int)posy;
        int y1 = min(y0 + 1, 31);
        float ft = posy - (float)y0;
        float o_[4];
#pragma unroll
        for (int j = 0; j < 4; ++j) {
            float v00 = tile[y0 * 32 + xi0[j]];
            float v01 = tile[y0 * 32 + xi1[j]];
            float v10 = tile[y1 * 32 + xi0[j]];
            float v11 = tile[y1 * 32 + xi1[j]];
            float top = v00 * (1.f - ft) + v10 * ft;
            float bot = v01 * (1.f - ft) + v11 * ft;
            float val = top * (1.f - xt[j]) + bot * xt[j];
            o_[j] = 1.f / (1.f + __expf(-val));
        }
        *reinterpret_cast<float4*>(out + ((size_t)bc * Wd + y) * Hd + tx * 4) =
            make_float4(o_[0], o_[1], o_[2], o_[3]);
    }
}

}  // namespace

extern "C" void kernel_launch(void* const* d_in, const int* in_sizes, int n_in,
                              void* d_out, int out_size, void* d_ws, size_t ws_size,
                              hipStream_t stream) {
    const float* input1 = (const float*)d_in[0];
    const float* input2 = (const float*)d_in[1];
    const float* conv_w = (const float*)d_in[2];
    const float* conv_b = (const float*)d_in[3];
    float* out = (float*)d_out;

    float* p1  = (float*)d_ws;
    float* p2t = p1 + (size_t)Bn * Cn * Nn;
    float* att = p2t + (size_t)Bn * Cn * Nn;

    pool1_kernel<<<dim3(Bn * Cn * Nn / 256), dim3(256), 0, stream>>>(input1, p1);
    convpool_kernel<<<dim3(512), dim3(512), 0, stream>>>(input2, conv_w, conv_b, p2t);
    attn_kernel<<<dim3(Nn), dim3(256), 0, stream>>>(p1, p2t, att);
    upsample_kernel<<<dim3(Bn * Cn), dim3(256), 0, stream>>>(att, out);
}

// Round 3
// 120.556 us; speedup vs baseline: 2.5218x; 1.0314x over previous
//
#include <hip/hip_runtime.h>
#include <math.h>

namespace {

constexpr int Bn = 8, Cn = 256, CIN = 128, Wd = 128, Hd = 128, ATTn = 32, Nn = ATTn * ATTn;

typedef __attribute__((ext_vector_type(8))) short short8;
typedef __attribute__((ext_vector_type(4))) float f32x4;

__device__ inline unsigned short bf16_rne(float f) {
    unsigned int u = __float_as_uint(f);
    unsigned int r = (u + 0x7FFFu + ((u >> 16) & 1u)) >> 16;
    return (unsigned short)r;
}

// ============ Fused front kernel: blocks [0,512) = conv+pool, [512,768) = pool1 ============
// convpool: block = half pooled row (b,oy,half); 8 waves; weights in registers; bf16 MFMA.
// pool1:    block = (b,oy); thread t: c = t&255, xh = t>>8; writes TRANSPOSED p1t[b][n][c].
__global__ __launch_bounds__(512) void front_kernel(const float* __restrict__ in1,
                                                    const float* __restrict__ in2,
                                                    const float* __restrict__ cw,
                                                    const float* __restrict__ cb,
                                                    float* __restrict__ p1t,
                                                    float* __restrict__ p2t) {
    __shared__ __align__(16) unsigned char sIn[2][16384];

    const int t = threadIdx.x;
    const int bid = blockIdx.x;

    if (bid >= 512) {
        // ---------------- pool1 branch: adaptive max+avg pool of in1 -> p1t[b][n][c] -------
        const int bid2 = bid - 512;            // 0..255
        const int b = bid2 >> 5, oy = bid2 & 31;
        const int c = t & 255, xh = t >> 8;    // xh 0..1, 16 ox each
        const float* src = in1 + (((size_t)(b * Cn + c) * Wd + oy * 4)) * Hd + xh * 64;
        float mx[16], sm[16];
#pragma unroll
        for (int q = 0; q < 16; ++q) { mx[q] = -INFINITY; sm[q] = 0.f; }
#pragma unroll
        for (int dy = 0; dy < 4; ++dy) {
            const float4* rp = reinterpret_cast<const float4*>(src + dy * Hd);
#pragma unroll
            for (int q = 0; q < 16; ++q) {
                float4 v = rp[q];
                mx[q] = fmaxf(mx[q], fmaxf(fmaxf(v.x, v.y), fmaxf(v.z, v.w)));
                sm[q] += (v.x + v.y) + (v.z + v.w);
            }
        }
        float* dst = p1t + ((size_t)b * Nn + oy * 32 + xh * 16) * Cn + c;
#pragma unroll
        for (int q = 0; q < 16; ++q)
            dst[(size_t)q * Cn] = mx[q] + sm[q] * (1.f / 16.f);
        return;
    }

    // ---------------- convpool branch: 1x1 conv (bf16 MFMA) + max+avg pool -> p2t ----------
    const int w = t >> 6;                 // wave 0..7
    const int l = t & 63;
    const int b = bid >> 6;
    const int oy = (bid >> 1) & 31;
    const int half = bid & 1;

    const int n_lo = l & 15;
    const int khi = l >> 4;

    short8 bfrag[2][4];
#pragma unroll
    for (int f = 0; f < 2; ++f) {
        const int n = w * 32 + f * 16 + n_lo;
#pragma unroll
        for (int kk = 0; kk < 4; ++kk) {
            const float* wp = cw + n * CIN + kk * 32 + khi * 8;
            float4 va = *reinterpret_cast<const float4*>(wp);
            float4 vb = *reinterpret_cast<const float4*>(wp + 4);
            short8 s;
            s[0] = (short)bf16_rne(va.x); s[1] = (short)bf16_rne(va.y);
            s[2] = (short)bf16_rne(va.z); s[3] = (short)bf16_rne(va.w);
            s[4] = (short)bf16_rne(vb.x); s[5] = (short)bf16_rne(vb.y);
            s[6] = (short)bf16_rne(vb.z); s[7] = (short)bf16_rne(vb.w);
            bfrag[f][kk] = s;
        }
    }
    const float bias2_0 = 2.f * cb[w * 32 + n_lo];
    const float bias2_1 = 2.f * cb[w * 32 + 16 + n_lo];

    const int xq = t & 3, dy = (t >> 2) & 3, k4 = t >> 4;
    const int row = oy * 4 + dy;
    const float* src = in2 + (((size_t)(b * CIN + k4 * 4)) * Wd + row) * Hd + half * 64 + xq * 4;

    float4 r0, r1, r2, r3;
#define STAGE_LOAD(g)                                                   \
    {   const float* p_ = src + (g) * 16;                               \
        r0 = *reinterpret_cast<const float4*>(p_);                      \
        r1 = *reinterpret_cast<const float4*>(p_ + Wd * Hd);            \
        r2 = *reinterpret_cast<const float4*>(p_ + 2 * Wd * Hd);        \
        r3 = *reinterpret_cast<const float4*>(p_ + 3 * Wd * Hd); }

#define WRQ(buf, dx, c0, c1, c2, c3)                                    \
    {   const int px_ = dy * 4 + (dx);                                  \
        uint2 u_;                                                       \
        u_.x = (unsigned int)bf16_rne(c0) | ((unsigned int)bf16_rne(c1) << 16); \
        u_.y = (unsigned int)bf16_rne(c2) | ((unsigned int)bf16_rne(c3) << 16); \
        const int off_ = (xq * 4096 + px_ * 256 + k4 * 8) ^ (((px_ & 7) << 4) ^ ((xq & 3) << 5)); \
        *reinterpret_cast<uint2*>(&sIn[buf][off_]) = u_; }

#define STAGE_WRITE(buf)                                                \
    {   WRQ(buf, 0, r0.x, r1.x, r2.x, r3.x)                             \
        WRQ(buf, 1, r0.y, r1.y, r2.y, r3.y)                             \
        WRQ(buf, 2, r0.z, r1.z, r2.z, r3.z)                             \
        WRQ(buf, 3, r0.w, r1.w, r2.w, r3.w) }

    STAGE_LOAD(0)
    STAGE_WRITE(0)
    __syncthreads();

    const int px = n_lo;
    for (int g = 0; g < 4; ++g) {
        const int buf = g & 1;
        if (g < 3) STAGE_LOAD(g + 1)

        const unsigned char* base = sIn[buf];
#pragma unroll
        for (int c = 0; c < 4; ++c) {
            const int swz = ((px & 7) << 4) ^ ((c & 3) << 5);
            f32x4 acc0 = {0.f, 0.f, 0.f, 0.f};
            f32x4 acc1 = {0.f, 0.f, 0.f, 0.f};
#pragma unroll
            for (int kk = 0; kk < 4; ++kk) {
                short8 a = *reinterpret_cast<const short8*>(
                    base + ((c * 4096 + px * 256 + kk * 64 + khi * 16) ^ swz));
                acc0 = __builtin_amdgcn_mfma_f32_16x16x32_bf16(a, bfrag[0][kk], acc0, 0, 0, 0);
                acc1 = __builtin_amdgcn_mfma_f32_16x16x32_bf16(a, bfrag[1][kk], acc1, 0, 0, 0);
            }
            float mx0 = fmaxf(fmaxf(acc0[0], acc0[1]), fmaxf(acc0[2], acc0[3]));
            float sm0 = (acc0[0] + acc0[1]) + (acc0[2] + acc0[3]);
            float mx1 = fmaxf(fmaxf(acc1[0], acc1[1]), fmaxf(acc1[2], acc1[3]));
            float sm1 = (acc1[0] + acc1[1]) + (acc1[2] + acc1[3]);
            mx0 = fmaxf(mx0, __shfl_xor(mx0, 16)); sm0 += __shfl_xor(sm0, 16);
            mx0 = fmaxf(mx0, __shfl_xor(mx0, 32)); sm0 += __shfl_xor(sm0, 32);
            mx1 = fmaxf(mx1, __shfl_xor(mx1, 16)); sm1 += __shfl_xor(sm1, 16);
            mx1 = fmaxf(mx1, __shfl_xor(mx1, 32)); sm1 += __shfl_xor(sm1, 32);
            if (l < 16) {
                const int cell = oy * 32 + half * 16 + g * 4 + c;
                float* dst = p2t + ((size_t)b * Nn + cell) * Cn + w * 32 + n_lo;
                dst[0]  = mx0 + sm0 * (1.f / 16.f) + bias2_0;
                dst[16] = mx1 + sm1 * (1.f / 16.f) + bias2_1;
            }
        }

        if (g < 3) STAGE_WRITE((g + 1) & 1)
        __syncthreads();
    }
#undef STAGE_LOAD
#undef STAGE_WRITE
#undef WRQ
}

// ---------------- Kernel 2: per-cell cross-batch attention -> att[b][c][n] ----------------
// 256 threads: w-dot on all threads (64 pairs x 4 c-chunks, interleaved c), shuffle softmax.
__global__ __launch_bounds__(256) void attn_kernel(const float* __restrict__ p1t,
                                                   const float* __restrict__ p2t,
                                                   float* __restrict__ att) {
    __shared__ float q[Bn][260];
    __shared__ float kk[Bn][260];
    __shared__ float wsm[Bn][8];
    const int n = blockIdx.x, t = threadIdx.x;

#pragma unroll
    for (int i = 0; i < 2; ++i) {
        const int f = t + i * 256;            // 0..511
        const int bb = f >> 6, cq = f & 63;
        const size_t off = ((size_t)bb * Nn + n) * Cn + cq * 4;
        *reinterpret_cast<float4*>(&q[bb][cq * 4])  = *reinterpret_cast<const float4*>(p1t + off);
        *reinterpret_cast<float4*>(&kk[bb][cq * 4]) = *reinterpret_cast<const float4*>(p2t + off);
    }
    __syncthreads();

    {
        const int chunk = t & 3, pair = t >> 2;
        const int e = pair & 7, bb = pair >> 3;
        float s = 0.f;
#pragma unroll
        for (int i = 0; i < 64; ++i)
            s = fmaf(q[bb][i * 4 + chunk], kk[e][i * 4 + chunk], s);
        s += __shfl_xor(s, 1);
        s += __shfl_xor(s, 2);
        s *= 0.17677669529663687f;            // 1/sqrt(32)
        float m = fmaxf(s, __shfl_xor(s, 4));
        m = fmaxf(m, __shfl_xor(m, 8));
        m = fmaxf(m, __shfl_xor(m, 16));
        float p = __expf(s - m);
        float d = p + __shfl_xor(p, 4);
        d += __shfl_xor(d, 8);
        d += __shfl_xor(d, 16);
        if (chunk == 0) wsm[bb][e] = p / d;
    }
    __syncthreads();

    float kv[8];
#pragma unroll
    for (int e = 0; e < 8; ++e) kv[e] = kk[e][t];
#pragma unroll
    for (int bb = 0; bb < 8; ++bb) {
        float s = 0.f;
#pragma unroll
        for (int e = 0; e < 8; ++e) s = fmaf(wsm[bb][e], kv[e], s);
        att[((size_t)bb * Cn + t) * Nn + n] = s;
    }
}

// ---------------- Kernel 3: bilinear upsample (align_corners) + sigmoid ----------------
__global__ __launch_bounds__(256) void upsample_kernel(const float* __restrict__ att,
                                                       float* __restrict__ out) {
    __shared__ float tile[ATTn * ATTn];
    int bc = blockIdx.x, t = threadIdx.x;
    reinterpret_cast<float4*>(tile)[t] =
        reinterpret_cast<const float4*>(att + (size_t)bc * Nn)[t];
    __syncthreads();

    int tx = t & 31, ty = t >> 5;
    int xi0[4], xi1[4];
    float xt[4];
#pragma unroll
    for (int j = 0; j < 4; ++j) {
        int x = tx * 4 + j;
        float pos = (float)x * (31.f / 127.f);
        int i0 = (int)pos;
        xi0[j] = i0;
        xi1[j] = min(i0 + 1, 31);
        xt[j] = pos - (float)i0;
    }

    for (int r = 0; r < 16; ++r) {
        int y = ty + r * 8;
        float posy = (float)y * (31.f / 127.f);
        int y0 = (int)posy;
        int y1 = min(y0 + 1, 31);
        float ft = posy - (float)y0;
        float o_[4];
#pragma unroll
        for (int j = 0; j < 4; ++j) {
            float v00 = tile[y0 * 32 + xi0[j]];
            float v01 = tile[y0 * 32 + xi1[j]];
            float v10 = tile[y1 * 32 + xi0[j]];
            float v11 = tile[y1 * 32 + xi1[j]];
            float top = v00 * (1.f - ft) + v10 * ft;
            float bot = v01 * (1.f - ft) + v11 * ft;
            float val = top * (1.f - xt[j]) + bot * xt[j];
            o_[j] = 1.f / (1.f + __expf(-val));
        }
        *reinterpret_cast<float4*>(out + ((size_t)bc * Wd + y) * Hd + tx * 4) =
            make_float4(o_[0], o_[1], o_[2], o_[3]);
    }
}

}  // namespace

extern "C" void kernel_launch(void* const* d_in, const int* in_sizes, int n_in,
                              void* d_out, int out_size, void* d_ws, size_t ws_size,
                              hipStream_t stream) {
    const float* input1 = (const float*)d_in[0];
    const float* input2 = (const float*)d_in[1];
    const float* conv_w = (const float*)d_in[2];
    const float* conv_b = (const float*)d_in[3];
    float* out = (float*)d_out;

    float* p1t = (float*)d_ws;                        // [B][N][C] 8 MB
    float* p2t = p1t + (size_t)Bn * Cn * Nn;          // [B][N][C] 8 MB
    float* att = p2t + (size_t)Bn * Cn * Nn;          // [B][C][N] 8 MB

    front_kernel<<<dim3(768), dim3(512), 0, stream>>>(input1, input2, conv_w, conv_b, p1t, p2t);
    attn_kernel<<<dim3(Nn), dim3(256), 0, stream>>>(p1t, p2t, att);
    upsample_kernel<<<dim3(Bn * Cn), dim3(256), 0, stream>>>(att, out);
}

// Round 4
// 110.751 us; speedup vs baseline: 2.7451x; 1.0885x over previous
//
#include <hip/hip_runtime.h>
#include <math.h>

namespace {

constexpr int Bn = 8, Cn = 256, CIN = 128, Wd = 128, Hd = 128, ATTn = 32, Nn = ATTn * ATTn;

typedef __attribute__((ext_vector_type(8))) short short8;
typedef __attribute__((ext_vector_type(4))) float f32x4;

__device__ inline unsigned short bf16_rne(float f) {
    unsigned int u = __float_as_uint(f);
    unsigned int r = (u + 0x7FFFu + ((u >> 16) & 1u)) >> 16;
    return (unsigned short)r;
}

__device__ inline int fsw(int px) { return (px ^ (px >> 3)) & 7; }

// ============ Fused front kernel ============
// blocks [0,256):    pool1  — block (b,oy); wave-private, coalesced, no barriers.
// blocks [256,1280): convpool — block (b,oy,xq); one-shot stage + 1 barrier + MFMA.
__global__ __launch_bounds__(512, 4) void front_kernel(const float* __restrict__ in1,
                                                       const float* __restrict__ in2,
                                                       const float* __restrict__ cw,
                                                       const float* __restrict__ cb,
                                                       float* __restrict__ p1t,
                                                       float* __restrict__ p2t) {
    __shared__ __align__(16) unsigned char smem[33792];

    const int t = threadIdx.x;
    const int bid = blockIdx.x;
    const int w = t >> 6;                 // wave 0..7
    const int l = t & 63;                 // lane

    if (bid < 256) {
        // ---------------- pool1: adaptive max+avg pool of in1 -> p1t[b][n][c] -------------
        const int b = bid >> 5, oy = bid & 31;
        float* tile = reinterpret_cast<float*>(smem) + w * 1056;   // [32 ox][33] f32
        const int x4 = l & 31, dyp = l >> 5;
        const float* base = in1 + ((size_t)(b * Cn + w * 32) * Wd + oy * 4 + dyp) * Hd + x4 * 4;
#pragma unroll 4
        for (int ch = 0; ch < 32; ++ch) {
            const float* p = base + (size_t)ch * Wd * Hd;
            f32x4 v0 = *reinterpret_cast<const f32x4*>(p);
            f32x4 v1 = *reinterpret_cast<const f32x4*>(p + 2 * Hd);
            float mx = fmaxf(fmaxf(fmaxf(v0[0], v0[1]), fmaxf(v0[2], v0[3])),
                             fmaxf(fmaxf(v1[0], v1[1]), fmaxf(v1[2], v1[3])));
            float sm = ((v0[0] + v0[1]) + (v0[2] + v0[3])) +
                       ((v1[0] + v1[1]) + (v1[2] + v1[3]));
            mx = fmaxf(mx, __shfl_xor(mx, 32));
            sm += __shfl_xor(sm, 32);
            if (l < 32) tile[x4 * 33 + ch] = mx + sm * (1.f / 16.f);
        }
        // wave-private tile: lgkmcnt ordering handled by compiler, no barrier needed
        const int cl = l & 31, oxp = l >> 5;
#pragma unroll
        for (int it = 0; it < 16; ++it) {
            const int ox = it * 2 + oxp;
            const float v = tile[ox * 33 + cl];
            p1t[((size_t)b * Nn + oy * 32 + ox) * Cn + w * 32 + cl] = v;
        }
        return;
    }

    // ---------------- convpool: 1x1 conv (bf16 MFMA) + max+avg pool -> p2t[b][n][c] -------
    const int bid2 = bid - 256;
    const int b = bid2 >> 7;
    const int r = bid2 & 127;
    const int oy = r >> 2, xq = r & 3;

    // ---- stage: 2 tasks/thread, 4 channel-strided float4 each (8x128B segments per instr)
    f32x4 ra[2][4];
    int x4v[2], rowv[2], k4v[2];
#pragma unroll
    for (int h = 0; h < 2; ++h) {
        const int i = t + h * 512;
        x4v[h] = i & 7; rowv[h] = (i >> 3) & 3; k4v[h] = i >> 5;
        const float* p = in2 + ((size_t)(b * CIN + k4v[h] * 4) * Wd + oy * 4 + rowv[h]) * Hd
                         + xq * 32 + x4v[h] * 4;
#pragma unroll
        for (int kk2 = 0; kk2 < 4; ++kk2)
            ra[h][kk2] = *reinterpret_cast<const f32x4*>(p + (size_t)kk2 * Wd * Hd);
    }

    // ---- B fragments (weights) in registers
    const int n_lo = l & 15;
    const int khi = l >> 4;
    short8 bfrag[2][4];
#pragma unroll
    for (int f = 0; f < 2; ++f) {
        const int n = w * 32 + f * 16 + n_lo;
#pragma unroll
        for (int kk = 0; kk < 4; ++kk) {
            const float* wp = cw + n * CIN + kk * 32 + khi * 8;
            f32x4 va = *reinterpret_cast<const f32x4*>(wp);
            f32x4 vb = *reinterpret_cast<const f32x4*>(wp + 4);
            short8 s;
            s[0] = (short)bf16_rne(va[0]); s[1] = (short)bf16_rne(va[1]);
            s[2] = (short)bf16_rne(va[2]); s[3] = (short)bf16_rne(va[3]);
            s[4] = (short)bf16_rne(vb[0]); s[5] = (short)bf16_rne(vb[1]);
            s[6] = (short)bf16_rne(vb[2]); s[7] = (short)bf16_rne(vb[3]);
            bfrag[f][kk] = s;
        }
    }
    const float bias2_0 = 2.f * cb[w * 32 + n_lo];
    const float bias2_1 = 2.f * cb[w * 32 + 16 + n_lo];

    // ---- transpose + swizzled LDS write: A[px][k] bf16, px = cell*16 + dy*4 + dx
#pragma unroll
    for (int h = 0; h < 2; ++h) {
#pragma unroll
        for (int j = 0; j < 4; ++j) {
            const int px = x4v[h] * 16 + rowv[h] * 4 + j;
            uint2 u;
            u.x = (unsigned int)bf16_rne(ra[h][0][j]) | ((unsigned int)bf16_rne(ra[h][1][j]) << 16);
            u.y = (unsigned int)bf16_rne(ra[h][2][j]) | ((unsigned int)bf16_rne(ra[h][3][j]) << 16);
            const int off = px * 256 + ((k4v[h] * 8) ^ (fsw(px) << 4));
            *reinterpret_cast<uint2*>(smem + off) = u;
        }
    }
    __syncthreads();

    // ---- per-wave: 8 cells x 2 n-tiles; K=128 inner, pool epilogue per cell
#pragma unroll
    for (int cl = 0; cl < 8; ++cl) {
        f32x4 acc0 = {0.f, 0.f, 0.f, 0.f};
        f32x4 acc1 = {0.f, 0.f, 0.f, 0.f};
        const int px = cl * 16 + n_lo;
        const int sw = fsw(px) << 4;
#pragma unroll
        for (int kk = 0; kk < 4; ++kk) {
            short8 a = *reinterpret_cast<const short8*>(
                smem + px * 256 + ((kk * 64 + khi * 16) ^ sw));
            acc0 = __builtin_amdgcn_mfma_f32_16x16x32_bf16(a, bfrag[0][kk], acc0, 0, 0, 0);
            acc1 = __builtin_amdgcn_mfma_f32_16x16x32_bf16(a, bfrag[1][kk], acc1, 0, 0, 0);
        }
        float mx0 = fmaxf(fmaxf(acc0[0], acc0[1]), fmaxf(acc0[2], acc0[3]));
        float sm0 = (acc0[0] + acc0[1]) + (acc0[2] + acc0[3]);
        float mx1 = fmaxf(fmaxf(acc1[0], acc1[1]), fmaxf(acc1[2], acc1[3]));
        float sm1 = (acc1[0] + acc1[1]) + (acc1[2] + acc1[3]);
        mx0 = fmaxf(mx0, __shfl_xor(mx0, 16)); sm0 += __shfl_xor(sm0, 16);
        mx0 = fmaxf(mx0, __shfl_xor(mx0, 32)); sm0 += __shfl_xor(sm0, 32);
        mx1 = fmaxf(mx1, __shfl_xor(mx1, 16)); sm1 += __shfl_xor(sm1, 16);
        mx1 = fmaxf(mx1, __shfl_xor(mx1, 32)); sm1 += __shfl_xor(sm1, 32);
        if (l < 16) {
            const int cell = oy * 32 + xq * 8 + cl;
            float* dst = p2t + ((size_t)b * Nn + cell) * Cn + w * 32 + n_lo;
            dst[0]  = mx0 + sm0 * (1.f / 16.f) + bias2_0;
            dst[16] = mx1 + sm1 * (1.f / 16.f) + bias2_1;
        }
    }
}

// ---------------- Kernel 2: per-cell cross-batch attention -> att[b][c][n] ----------------
__global__ __launch_bounds__(256) void attn_kernel(const float* __restrict__ p1t,
                                                   const float* __restrict__ p2t,
                                                   float* __restrict__ att) {
    __shared__ float q[Bn][260];
    __shared__ float kk[Bn][260];
    __shared__ float wsm[Bn][8];
    const int n = blockIdx.x, t = threadIdx.x;

#pragma unroll
    for (int i = 0; i < 2; ++i) {
        const int f = t + i * 256;
        const int bb = f >> 6, cq = f & 63;
        const size_t off = ((size_t)bb * Nn + n) * Cn + cq * 4;
        *reinterpret_cast<float4*>(&q[bb][cq * 4])  = *reinterpret_cast<const float4*>(p1t + off);
        *reinterpret_cast<float4*>(&kk[bb][cq * 4]) = *reinterpret_cast<const float4*>(p2t + off);
    }
    __syncthreads();

    {
        const int chunk = t & 3, pair = t >> 2;
        const int e = pair & 7, bb = pair >> 3;
        float s = 0.f;
#pragma unroll
        for (int i = 0; i < 64; ++i)
            s = fmaf(q[bb][i * 4 + chunk], kk[e][i * 4 + chunk], s);
        s += __shfl_xor(s, 1);
        s += __shfl_xor(s, 2);
        s *= 0.17677669529663687f;            // 1/sqrt(32)
        float m = fmaxf(s, __shfl_xor(s, 4));
        m = fmaxf(m, __shfl_xor(m, 8));
        m = fmaxf(m, __shfl_xor(m, 16));
        float p = __expf(s - m);
        float d = p + __shfl_xor(p, 4);
        d += __shfl_xor(d, 8);
        d += __shfl_xor(d, 16);
        if (chunk == 0) wsm[bb][e] = p / d;
    }
    __syncthreads();

    float kv[8];
#pragma unroll
    for (int e = 0; e < 8; ++e) kv[e] = kk[e][t];
#pragma unroll
    for (int bb = 0; bb < 8; ++bb) {
        float s = 0.f;
#pragma unroll
        for (int e = 0; e < 8; ++e) s = fmaf(wsm[bb][e], kv[e], s);
        att[((size_t)bb * Cn + t) * Nn + n] = s;
    }
}

// ---------------- Kernel 3: bilinear upsample (align_corners) + sigmoid ----------------
__global__ __launch_bounds__(256) void upsample_kernel(const float* __restrict__ att,
                                                       float* __restrict__ out) {
    __shared__ float tile[ATTn * ATTn];
    int bc = blockIdx.x, t = threadIdx.x;
    reinterpret_cast<float4*>(tile)[t] =
        reinterpret_cast<const float4*>(att + (size_t)bc * Nn)[t];
    __syncthreads();

    int tx = t & 31, ty = t >> 5;
    int xi0[4], xi1[4];
    float xt[4];
#pragma unroll
    for (int j = 0; j < 4; ++j) {
        int x = tx * 4 + j;
        float pos = (float)x * (31.f / 127.f);
        int i0 = (int)pos;
        xi0[j] = i0;
        xi1[j] = min(i0 + 1, 31);
        xt[j] = pos - (float)i0;
    }

    for (int r = 0; r < 16; ++r) {
        int y = ty + r * 8;
        float posy = (float)y * (31.f / 127.f);
        int y0 = (int)posy;
        int y1 = min(y0 + 1, 31);
        float ft = posy - (float)y0;
        float o_[4];
#pragma unroll
        for (int j = 0; j < 4; ++j) {
            float v00 = tile[y0 * 32 + xi0[j]];
            float v01 = tile[y0 * 32 + xi1[j]];
            float v10 = tile[y1 * 32 + xi0[j]];
            float v11 = tile[y1 * 32 + xi1[j]];
            float top = v00 * (1.f - ft) + v10 * ft;
            float bot = v01 * (1.f - ft) + v11 * ft;
            float val = top * (1.f - xt[j]) + bot * xt[j];
            o_[j] = 1.f / (1.f + __expf(-val));
        }
        *reinterpret_cast<float4*>(out + ((size_t)bc * Wd + y) * Hd + tx * 4) =
            make_float4(o_[0], o_[1], o_[2], o_[3]);
    }
}

}  // namespace

extern "C" void kernel_launch(void* const* d_in, const int* in_sizes, int n_in,
                              void* d_out, int out_size, void* d_ws, size_t ws_size,
                              hipStream_t stream) {
    const float* input1 = (const float*)d_in[0];
    const float* input2 = (const float*)d_in[1];
    const float* conv_w = (const float*)d_in[2];
    const float* conv_b = (const float*)d_in[3];
    float* out = (float*)d_out;

    float* p1t = (float*)d_ws;                        // [B][N][C] 8 MB
    float* p2t = p1t + (size_t)Bn * Cn * Nn;          // [B][N][C] 8 MB
    float* att = p2t + (size_t)Bn * Cn * Nn;          // [B][C][N] 8 MB

    front_kernel<<<dim3(1280), dim3(512), 0, stream>>>(input1, input2, conv_w, conv_b, p1t, p2t);
    attn_kernel<<<dim3(Nn), dim3(256), 0, stream>>>(p1t, p2t, att);
    upsample_kernel<<<dim3(Bn * Cn), dim3(256), 0, stream>>>(att, out);
}